// Round 2
// baseline (174.982 us; speedup 1.0000x reference)
//
#include <hip/hip_runtime.h>
#include <math.h>

// Problem constants (from reference setup_inputs)
#define B 64
#define S 2048
#define H 1024
#define SPLIT 16
#define ROWS_PER_BLOCK (S / SPLIT)              // 128
#define THREADS 256
#define WAVES 4
#define ROWS_PER_WAVE (ROWS_PER_BLOCK / WAVES)  // 32
#define PAIRS (ROWS_PER_WAVE / 2)               // 16

// ---------------------------------------------------------------------------
// Pass 1: fused score + online-softmax context accumulation.
// One block = one (b, split) chunk of 128 sequence rows. Each wave owns whole
// rows (lane l holds h = c*256 + l*4 + j, c=0..3 j=0..3 -> 16 floats/lane).
// 2 rows per step, double-buffered loads => ~8-16 KB in flight per wave.
// ---------------------------------------------------------------------------

#define LOADP(EBUF, pidx) do {                                                  \
    const int sL0_ = s_base + ((pidx) * 2)     * WAVES;                         \
    const int sL1_ = s_base + ((pidx) * 2 + 1) * WAVES;                         \
    const float4* r0_ = (const float4*)(enc + ((size_t)b * S + sL0_) * H);      \
    const float4* r1_ = (const float4*)(enc + ((size_t)b * S + sL1_) * H);      \
    _Pragma("unroll")                                                           \
    for (int c_ = 0; c_ < 4; ++c_) {                                            \
      EBUF[c_]     = r0_[c_ * 64 + lane];                                       \
      EBUF[4 + c_] = r1_[c_ * 64 + lane];                                       \
    }                                                                           \
  } while (0)

#define PROC(EBUF, pidx) do {                                                   \
    float p0_ = 0.f, p1_ = 0.f;                                                 \
    _Pragma("unroll")                                                           \
    for (int c_ = 0; c_ < 4; ++c_) {                                            \
      p0_ += EBUF[c_].x * dec[c_].x + EBUF[c_].y * dec[c_].y +                  \
             EBUF[c_].z * dec[c_].z + EBUF[c_].w * dec[c_].w;                   \
      p1_ += EBUF[4+c_].x * dec[c_].x + EBUF[4+c_].y * dec[c_].y +              \
             EBUF[4+c_].z * dec[c_].z + EBUF[4+c_].w * dec[c_].w;               \
    }                                                                           \
    _Pragma("unroll")                                                           \
    for (int off_ = 32; off_ >= 1; off_ >>= 1) {                                \
      p0_ += __shfl_xor(p0_, off_, 64);                                         \
      p1_ += __shfl_xor(p1_, off_, 64);                                         \
    }                                                                           \
    const int sA_ = s_base + ((pidx) * 2) * WAVES;                              \
    if (lane == 0) {                                                            \
      attn_raw[b * S + sA_]         = p0_;                                      \
      attn_raw[b * S + sA_ + WAVES] = p1_;                                      \
    }                                                                           \
    const float mn_ = fmaxf(m, fmaxf(p0_, p1_));                                \
    if (mn_ > m) {                                                              \
      const float f_ = expf(m - mn_);                                           \
      Z *= f_;                                                                  \
      _Pragma("unroll")                                                         \
      for (int k_ = 0; k_ < 16; ++k_) ctx[k_] *= f_;                            \
      m = mn_;                                                                  \
    }                                                                           \
    const float e0_ = expf(p0_ - m), e1_ = expf(p1_ - m);                       \
    Z += e0_ + e1_;                                                             \
    _Pragma("unroll")                                                           \
    for (int c_ = 0; c_ < 4; ++c_) {                                            \
      ctx[c_*4+0] += e0_ * EBUF[c_].x + e1_ * EBUF[4+c_].x;                     \
      ctx[c_*4+1] += e0_ * EBUF[c_].y + e1_ * EBUF[4+c_].y;                     \
      ctx[c_*4+2] += e0_ * EBUF[c_].z + e1_ * EBUF[4+c_].z;                     \
      ctx[c_*4+3] += e0_ * EBUF[c_].w + e1_ * EBUF[4+c_].w;                     \
    }                                                                           \
  } while (0)

__global__ __launch_bounds__(THREADS, 4)
void luong_pass1(const float* __restrict__ dec_h,
                 const float* __restrict__ dec_c,
                 const float* __restrict__ enc,
                 float* __restrict__ attn_raw,   // d_out + B*H, raw scores
                 float* __restrict__ ctx_part,   // [B][SPLIT][H]
                 float* __restrict__ mz_part) {  // [B][SPLIT][2]
  const int bid  = blockIdx.x;
  const int b    = bid / SPLIT;
  const int sp   = bid % SPLIT;
  const int t    = threadIdx.x;
  const int w    = t >> 6;     // wave id 0..3
  const int lane = t & 63;

  // dec = dec_h + dec_c, distributed 16 elems per lane (same for all waves)
  float4 dec[4];
  const float4* dh = (const float4*)(dec_h + (size_t)b * H);
  const float4* dc = (const float4*)(dec_c + (size_t)b * H);
#pragma unroll
  for (int c = 0; c < 4; ++c) {
    float4 a  = dh[c * 64 + lane];
    float4 bb = dc[c * 64 + lane];
    dec[c] = make_float4(a.x + bb.x, a.y + bb.y, a.z + bb.z, a.w + bb.w);
  }

  float m = -INFINITY;
  float Z = 0.f;
  float ctx[16];
#pragma unroll
  for (int k = 0; k < 16; ++k) ctx[k] = 0.f;

  const int s_base = sp * ROWS_PER_BLOCK + w;

  float4 eA[8], eB[8];
  LOADP(eA, 0);
  for (int p2 = 0; p2 < PAIRS / 2; ++p2) {
    LOADP(eB, 2 * p2 + 1);
    PROC(eA, 2 * p2);
    if (p2 < PAIRS / 2 - 1) LOADP(eA, 2 * p2 + 2);
    PROC(eB, 2 * p2 + 1);
  }

  // ---- combine the 4 waves of this block via LDS ----
  __shared__ float ctx_lds[WAVES][H];  // 16 KiB
  __shared__ float mzs[WAVES][2];
#pragma unroll
  for (int c = 0; c < 4; ++c) {
    float4 v = make_float4(ctx[c * 4 + 0], ctx[c * 4 + 1],
                           ctx[c * 4 + 2], ctx[c * 4 + 3]);
    ((float4*)&ctx_lds[w][c * 256])[lane] = v;
  }
  if (lane == 0) { mzs[w][0] = m; mzs[w][1] = Z; }
  __syncthreads();

  const float M = fmaxf(fmaxf(mzs[0][0], mzs[1][0]),
                        fmaxf(mzs[2][0], mzs[3][0]));
  float fac[WAVES];
  float Zb = 0.f;
#pragma unroll
  for (int i = 0; i < WAVES; ++i) {
    fac[i] = expf(mzs[i][0] - M);
    Zb += mzs[i][1] * fac[i];
  }

  float* outp = ctx_part + ((size_t)b * SPLIT + sp) * H;
#pragma unroll
  for (int q = 0; q < 4; ++q) {
    const int h = q * 256 + t;
    float v = 0.f;
#pragma unroll
    for (int i = 0; i < WAVES; ++i) v += ctx_lds[i][h] * fac[i];
    outp[h] = v;
  }
  if (t == 0) {
    mz_part[(b * SPLIT + sp) * 2 + 0] = M;
    mz_part[(b * SPLIT + sp) * 2 + 1] = Zb;
  }
}

// ---------------------------------------------------------------------------
// Pass 2: merge the SPLIT partials per batch -> context vector + final (M, Z)
// ---------------------------------------------------------------------------
__global__ __launch_bounds__(256)
void luong_combine(const float* __restrict__ ctx_part,
                   const float* __restrict__ mz_part,
                   float* __restrict__ ctx_out,    // d_out
                   float* __restrict__ mz_final) { // [B][2]
  const int b = blockIdx.x;
  const int t = threadIdx.x;

  float m_i[SPLIT], z_i[SPLIT];
  float M = -INFINITY;
#pragma unroll
  for (int i = 0; i < SPLIT; ++i) {
    m_i[i] = mz_part[(b * SPLIT + i) * 2 + 0];
    z_i[i] = mz_part[(b * SPLIT + i) * 2 + 1];
    M = fmaxf(M, m_i[i]);
  }
  float fac[SPLIT];
  float Z = 0.f;
#pragma unroll
  for (int i = 0; i < SPLIT; ++i) {
    fac[i] = expf(m_i[i] - M);
    Z += z_i[i] * fac[i];
  }
  const float invZ = 1.f / Z;

#pragma unroll
  for (int q = 0; q < 4; ++q) {
    const int h = q * 256 + t;
    float v = 0.f;
#pragma unroll
    for (int i = 0; i < SPLIT; ++i)
      v += ctx_part[((size_t)(b * SPLIT + i)) * H + h] * fac[i];
    ctx_out[(size_t)b * H + h] = v * invZ;
  }
  if (t == 0) {
    mz_final[2 * b + 0] = M;
    mz_final[2 * b + 1] = Z;
  }
}

// ---------------------------------------------------------------------------
// Pass 3: normalize raw scores in place -> softmax attention weights
// ---------------------------------------------------------------------------
__global__ __launch_bounds__(256)
void luong_fixup(float* __restrict__ attn,
                 const float* __restrict__ mz_final) {
  const int idx = blockIdx.x * blockDim.x + threadIdx.x;
  if (idx >= B * S) return;
  const int b = idx >> 11;  // S = 2048
  const float M = mz_final[2 * b + 0];
  const float Z = mz_final[2 * b + 1];
  attn[idx] = expf(attn[idx] - M) / Z;
}

extern "C" void kernel_launch(void* const* d_in, const int* in_sizes, int n_in,
                              void* d_out, int out_size, void* d_ws, size_t ws_size,
                              hipStream_t stream) {
  const float* dec_h = (const float*)d_in[0];
  const float* dec_c = (const float*)d_in[1];
  const float* enc   = (const float*)d_in[2];

  float* ctx_out = (float*)d_out;            // [B][H]
  float* attn    = (float*)d_out + B * H;    // [B][S]

  float* ctx_part = (float*)d_ws;                             // B*SPLIT*H floats = 4 MiB
  float* mz_part  = ctx_part + (size_t)B * SPLIT * H;         // B*SPLIT*2
  float* mz_final = mz_part + (size_t)B * SPLIT * 2;          // B*2

  luong_pass1<<<B * SPLIT, THREADS, 0, stream>>>(dec_h, dec_c, enc, attn,
                                                 ctx_part, mz_part);
  luong_combine<<<B, 256, 0, stream>>>(ctx_part, mz_part, ctx_out, mz_final);
  luong_fixup<<<(B * S + 255) / 256, 256, 0, stream>>>(attn, mz_final);
}

// Round 3
// 116.125 us; speedup vs baseline: 1.5068x; 1.5068x over previous
//
#include <hip/hip_runtime.h>
#include <math.h>

// Problem constants (from reference setup_inputs)
#define B 64
#define S 2048
#define H 1024
#define SPLIT 16
#define ROWS_PER_BLOCK (S / SPLIT)              // 128
#define THREADS 256
#define WAVES 4
#define ROWS_PER_WAVE (ROWS_PER_BLOCK / WAVES)  // 32

// ---------------------------------------------------------------------------
// Pass 1: fused score + online-softmax context accumulation.
// One block = one (b, split) chunk of 128 sequence rows. Each wave owns whole
// rows (lane l holds h = c*256 + l*4 + j, c=0..3 j=0..3 -> 16 floats/lane).
// 3-slot register rotation, depth-2 row prefetch => 8 KB in flight per wave,
// ~128 KB/CU at 16 waves/CU. All buffer indices are compile-time constants
// (dynamic indexing would go to scratch — rule #20).
// VGPR budget: buf 48 + dec 16 + ctx 16 + ~25 temps ≈ 105 < 128 cap of (256,4).
// ---------------------------------------------------------------------------
__global__ __launch_bounds__(THREADS, 4)
void luong_pass1(const float* __restrict__ dec_h,
                 const float* __restrict__ dec_c,
                 const float* __restrict__ enc,
                 float* __restrict__ attn_raw,   // d_out + B*H, raw scores
                 float* __restrict__ ctx_part,   // [B][SPLIT][H]
                 float* __restrict__ mz_part) {  // [B][SPLIT][2]
  const int bid  = blockIdx.x;
  const int b    = bid / SPLIT;
  const int sp   = bid % SPLIT;
  const int t    = threadIdx.x;
  const int w    = t >> 6;     // wave id 0..3
  const int lane = t & 63;

  // dec = dec_h + dec_c, distributed 16 elems per lane (same for all waves)
  float4 dec[4];
  const float4* dh = (const float4*)(dec_h + (size_t)b * H);
  const float4* dc = (const float4*)(dec_c + (size_t)b * H);
#pragma unroll
  for (int c = 0; c < 4; ++c) {
    float4 a  = dh[c * 64 + lane];
    float4 bb = dc[c * 64 + lane];
    dec[c] = make_float4(a.x + bb.x, a.y + bb.y, a.z + bb.z, a.w + bb.w);
  }

  float m = -INFINITY;
  float Z = 0.f;
  float ctx[16];
#pragma unroll
  for (int k = 0; k < 16; ++k) ctx[k] = 0.f;

  const int s_base = sp * ROWS_PER_BLOCK + w;
  // wave-local row r lives at enc[b][s_base + r*WAVES][*]
  const float4* ebase = (const float4*)(enc + ((size_t)b * S + s_base) * H);

  float4 buf[3][4];  // 3 slots x 1 row (16 floats/lane)

#define LOADR(SL, R) do {                                                      \
    const float4* rp_ = ebase + (size_t)(R) * (WAVES * (H / 4));               \
    _Pragma("unroll")                                                          \
    for (int c_ = 0; c_ < 4; ++c_) buf[SL][c_] = rp_[c_ * 64 + lane];          \
  } while (0)

#define PROCR(SL, R) do {                                                      \
    float p_ = 0.f;                                                            \
    _Pragma("unroll")                                                          \
    for (int c_ = 0; c_ < 4; ++c_)                                             \
      p_ += buf[SL][c_].x * dec[c_].x + buf[SL][c_].y * dec[c_].y +            \
            buf[SL][c_].z * dec[c_].z + buf[SL][c_].w * dec[c_].w;             \
    _Pragma("unroll")                                                          \
    for (int off_ = 32; off_ >= 1; off_ >>= 1)                                 \
      p_ += __shfl_xor(p_, off_, 64);                                          \
    if (lane == 0) attn_raw[b * S + s_base + (R) * WAVES] = p_;                \
    if (p_ > m) {                                                              \
      const float f_ = expf(m - p_);                                           \
      Z *= f_;                                                                 \
      _Pragma("unroll")                                                        \
      for (int k_ = 0; k_ < 16; ++k_) ctx[k_] *= f_;                           \
      m = p_;                                                                  \
    }                                                                          \
    const float e_ = expf(p_ - m);                                             \
    Z += e_;                                                                   \
    _Pragma("unroll")                                                          \
    for (int c_ = 0; c_ < 4; ++c_) {                                           \
      ctx[c_ * 4 + 0] += e_ * buf[SL][c_].x;                                   \
      ctx[c_ * 4 + 1] += e_ * buf[SL][c_].y;                                   \
      ctx[c_ * 4 + 2] += e_ * buf[SL][c_].z;                                   \
      ctx[c_ * 4 + 3] += e_ * buf[SL][c_].w;                                   \
    }                                                                          \
  } while (0)

  // prologue: rows 0,1 in flight
  LOADR(0, 0);
  LOADR(1, 1);
  // main loop: rows 0..29, always 2 rows of loads outstanding
  for (int i = 0; i < ROWS_PER_WAVE - 2; i += 3) {
    LOADR(2, i + 2);
    PROCR(0, i);
    LOADR(0, i + 3);
    PROCR(1, i + 1);
    LOADR(1, i + 4);
    PROCR(2, i + 2);
  }
  // epilogue: rows 30, 31 (already loaded into slots 0, 1)
  PROCR(0, ROWS_PER_WAVE - 2);
  PROCR(1, ROWS_PER_WAVE - 1);

#undef LOADR
#undef PROCR

  // ---- combine the 4 waves of this block via LDS ----
  __shared__ float ctx_lds[WAVES][H];  // 16 KiB
  __shared__ float mzs[WAVES][2];
#pragma unroll
  for (int c = 0; c < 4; ++c) {
    float4 v = make_float4(ctx[c * 4 + 0], ctx[c * 4 + 1],
                           ctx[c * 4 + 2], ctx[c * 4 + 3]);
    ((float4*)&ctx_lds[w][c * 256])[lane] = v;
  }
  if (lane == 0) { mzs[w][0] = m; mzs[w][1] = Z; }
  __syncthreads();

  const float M = fmaxf(fmaxf(mzs[0][0], mzs[1][0]),
                        fmaxf(mzs[2][0], mzs[3][0]));
  float fac[WAVES];
  float Zb = 0.f;
#pragma unroll
  for (int i = 0; i < WAVES; ++i) {
    fac[i] = expf(mzs[i][0] - M);
    Zb += mzs[i][1] * fac[i];
  }

  float* outp = ctx_part + ((size_t)b * SPLIT + sp) * H;
#pragma unroll
  for (int q = 0; q < 4; ++q) {
    const int h = q * 256 + t;
    float v = 0.f;
#pragma unroll
    for (int i = 0; i < WAVES; ++i) v += ctx_lds[i][h] * fac[i];
    outp[h] = v;
  }
  if (t == 0) {
    mz_part[(b * SPLIT + sp) * 2 + 0] = M;
    mz_part[(b * SPLIT + sp) * 2 + 1] = Zb;
  }
}

// ---------------------------------------------------------------------------
// Pass 2: merge the SPLIT partials per batch -> context vector + final (M, Z)
// ---------------------------------------------------------------------------
__global__ __launch_bounds__(256)
void luong_combine(const float* __restrict__ ctx_part,
                   const float* __restrict__ mz_part,
                   float* __restrict__ ctx_out,    // d_out
                   float* __restrict__ mz_final) { // [B][2]
  const int b = blockIdx.x;
  const int t = threadIdx.x;

  float m_i[SPLIT], z_i[SPLIT];
  float M = -INFINITY;
#pragma unroll
  for (int i = 0; i < SPLIT; ++i) {
    m_i[i] = mz_part[(b * SPLIT + i) * 2 + 0];
    z_i[i] = mz_part[(b * SPLIT + i) * 2 + 1];
    M = fmaxf(M, m_i[i]);
  }
  float fac[SPLIT];
  float Z = 0.f;
#pragma unroll
  for (int i = 0; i < SPLIT; ++i) {
    fac[i] = expf(m_i[i] - M);
    Z += z_i[i] * fac[i];
  }
  const float invZ = 1.f / Z;

#pragma unroll
  for (int q = 0; q < 4; ++q) {
    const int h = q * 256 + t;
    float v = 0.f;
#pragma unroll
    for (int i = 0; i < SPLIT; ++i)
      v += ctx_part[((size_t)(b * SPLIT + i)) * H + h] * fac[i];
    ctx_out[(size_t)b * H + h] = v * invZ;
  }
  if (t == 0) {
    mz_final[2 * b + 0] = M;
    mz_final[2 * b + 1] = Z;
  }
}

// ---------------------------------------------------------------------------
// Pass 3: normalize raw scores in place -> softmax attention weights
// ---------------------------------------------------------------------------
__global__ __launch_bounds__(256)
void luong_fixup(float* __restrict__ attn,
                 const float* __restrict__ mz_final) {
  const int idx = blockIdx.x * blockDim.x + threadIdx.x;
  if (idx >= B * S) return;
  const int b = idx >> 11;  // S = 2048
  const float M = mz_final[2 * b + 0];
  const float Z = mz_final[2 * b + 1];
  attn[idx] = expf(attn[idx] - M) / Z;
}

extern "C" void kernel_launch(void* const* d_in, const int* in_sizes, int n_in,
                              void* d_out, int out_size, void* d_ws, size_t ws_size,
                              hipStream_t stream) {
  const float* dec_h = (const float*)d_in[0];
  const float* dec_c = (const float*)d_in[1];
  const float* enc   = (const float*)d_in[2];

  float* ctx_out = (float*)d_out;            // [B][H]
  float* attn    = (float*)d_out + B * H;    // [B][S]

  float* ctx_part = (float*)d_ws;                             // B*SPLIT*H floats = 4 MiB
  float* mz_part  = ctx_part + (size_t)B * SPLIT * H;         // B*SPLIT*2
  float* mz_final = mz_part + (size_t)B * SPLIT * 2;          // B*2

  luong_pass1<<<B * SPLIT, THREADS, 0, stream>>>(dec_h, dec_c, enc, attn,
                                                 ctx_part, mz_part);
  luong_combine<<<B, 256, 0, stream>>>(ctx_part, mz_part, ctx_out, mz_final);
  luong_fixup<<<(B * S + 255) / 256, 256, 0, stream>>>(attn, mz_final);
}